// Round 1
// baseline (2534.374 us; speedup 1.0000x reference)
//
#include <hip/hip_runtime.h>

#define OFFX 0.0f
#define OFFY -40.0f
#define OFFZ -3.0f
#define BNEPS 1e-3f
#define KC 32   // knn chunks over known points
#define NCH 16  // bn partial chunks

// ---------------- keys ----------------
__global__ void keys_k(const int* __restrict__ coords, int n, int D, int H, int W,
                       int* __restrict__ keys) {
  int i = blockIdx.x * 256 + threadIdx.x;
  if (i < n) {
    const int* c = coords + (size_t)i * 4;
    keys[i] = ((c[0] * D + c[1]) * H + c[2]) * W + c[3];
  }
}

// ---------------- neighbor tables (subm: scale=1, stride: scale=2) ----------------
__global__ void nbr_k(const int* __restrict__ coords, int np, const int* __restrict__ keys, int nk,
                      int D, int H, int W, int scale, int* __restrict__ nbr) {
  int t = blockIdx.x * 256 + threadIdx.x;
  if (t >= np * 27) return;
  int p = t / 27, k = t % 27;
  int kz = k / 9 - 1, ky = (k / 3) % 3 - 1, kx = k % 3 - 1;
  const int* c = coords + (size_t)p * 4;
  int z = c[1] * scale + kz, y = c[2] * scale + ky, x = c[3] * scale + kx;
  int r = -1;
  if (z >= 0 && z < D && y >= 0 && y < H && x >= 0 && x < W) {
    int q = ((c[0] * D + z) * H + y) * W + x;
    int lo = 0, hi = nk;
    while (lo < hi) { int m = (lo + hi) >> 1; if (keys[m] < q) lo = m + 1; else hi = m; }
    if (lo < nk && keys[lo] == q) r = lo;
  }
  nbr[t] = r;
}

// ---------------- sparse 3x3x3 conv ----------------
// block = 256 threads (4 waves), 32 points per block (8 per wave).
// per tap: stage w[k] (CIN x COUT) in LDS, gather feature rows via float4 broadcast loads.
template<int CIN, int COUT>
__global__ void conv_k(const float* __restrict__ feats, const int* __restrict__ nbr,
                       const float* __restrict__ w, int n, float* __restrict__ out) {
  constexpr int PR = 64 / COUT;  // point-rows per wave row
  constexpr int NI = 8 / PR;     // points per thread
  __shared__ __align__(16) float wlds[CIN * COUT];
  int tid = threadIdx.x;
  int wave = tid >> 6, lane = tid & 63;
  int co = lane % COUT, j = lane / COUT;
  int pbase = blockIdx.x * 32 + wave * 8;
  float acc[NI];
#pragma unroll
  for (int i = 0; i < NI; i++) acc[i] = 0.f;
  for (int k = 0; k < 27; k++) {
    __syncthreads();
    for (int i = tid; i < CIN * COUT / 4; i += 256)
      ((float4*)wlds)[i] = ((const float4*)w)[(size_t)k * (CIN * COUT / 4) + i];
    __syncthreads();
#pragma unroll
    for (int i = 0; i < NI; i++) {
      int p = pbase + i * PR + j;
      if (p >= n) continue;
      int idx = nbr[(size_t)p * 27 + k];
      if (idx < 0) continue;
      const float* fr = feats + (size_t)idx * CIN;
#pragma unroll
      for (int c4 = 0; c4 < CIN / 4; c4++) {
        float4 fv = *(const float4*)(fr + c4 * 4);
        acc[i] = fmaf(fv.x, wlds[(c4 * 4 + 0) * COUT + co], acc[i]);
        acc[i] = fmaf(fv.y, wlds[(c4 * 4 + 1) * COUT + co], acc[i]);
        acc[i] = fmaf(fv.z, wlds[(c4 * 4 + 2) * COUT + co], acc[i]);
        acc[i] = fmaf(fv.w, wlds[(c4 * 4 + 3) * COUT + co], acc[i]);
      }
    }
  }
#pragma unroll
  for (int i = 0; i < NI; i++) {
    int p = pbase + i * PR + j;
    if (p < n) out[(size_t)p * COUT + co] = acc[i];
  }
}

// ---------------- batchnorm (train mode): partial sums then finalize+apply ----------------
__global__ void bnpart_k(const float* __restrict__ pre, int n, int C, float* __restrict__ part) {
  __shared__ float l1[256], l2[256];
  int t = threadIdx.x;
  int c = t % C, j = t / C;
  int per = (n + NCH - 1) / NCH;
  int rs = blockIdx.y * per;
  int re = rs + per; if (re > n) re = n;
  float s1 = 0.f, s2 = 0.f;
  for (int r = rs + j; r < re; r += 256 / C) {
    float v = pre[(size_t)r * C + c];
    s1 += v; s2 += v * v;
  }
  l1[t] = s1; l2[t] = s2;
  for (int s = 128; s >= C; s >>= 1) {
    __syncthreads();
    if (t < s) { l1[t] += l1[t + s]; l2[t] += l2[t + s]; }
  }
  __syncthreads();
  if (t < C) {
    part[((size_t)blockIdx.y * C + t) * 2] = l1[t];
    part[((size_t)blockIdx.y * C + t) * 2 + 1] = l2[t];
  }
}

__global__ void bnapply_k(const float* __restrict__ pre, const float* __restrict__ part,
                          const float* __restrict__ bnp, int n, int C, float* __restrict__ post) {
  __shared__ float sc[128];
  int t = threadIdx.x;
  if (t < C) {
    float s1 = 0.f, s2 = 0.f;
    for (int ch = 0; ch < NCH; ch++) {
      s1 += part[((size_t)ch * C + t) * 2];
      s2 += part[((size_t)ch * C + t) * 2 + 1];
    }
    float m = s1 / n;
    float v = s2 / n - m * m;
    float scale = bnp[t] / sqrtf(v + BNEPS);
    sc[t] = scale;
    sc[64 + t] = bnp[C + t] - m * scale;
  }
  __syncthreads();
  size_t i = (size_t)blockIdx.x * 256 + t;
  if (i < (size_t)n * C) {
    int c = (int)(i % C);
    float v = pre[i] * sc[c] + sc[64 + c];
    post[i] = v > 0.f ? v : 0.f;
  }
}

// ---------------- points_mean ----------------
__global__ void pm_k(const float* __restrict__ vf, const int* __restrict__ c0, int n0,
                     float* __restrict__ pm, float* __restrict__ out1) {
  int i = blockIdx.x * 256 + threadIdx.x;
  if (i >= n0) return;
  float b = (float)c0[(size_t)i * 4];
  float x = vf[(size_t)i * 4], y = vf[(size_t)i * 4 + 1], z = vf[(size_t)i * 4 + 2];
  pm[(size_t)i * 4] = b; pm[(size_t)i * 4 + 1] = x; pm[(size_t)i * 4 + 2] = y; pm[(size_t)i * 4 + 3] = z;
  out1[(size_t)i * 4] = b; out1[(size_t)i * 4 + 1] = x; out1[(size_t)i * 4 + 2] = y; out1[(size_t)i * 4 + 3] = z;
}

// ---------------- 3-NN: per-chunk top-3 then merge ----------------
__global__ void knn_part_k(const float* __restrict__ pm, int n0, const int* __restrict__ coords, int nl,
                           float vx, float vy, float vz,
                           float* __restrict__ pd, int* __restrict__ pi) {
  __shared__ __align__(16) float4 kp[256];
  int t = threadIdx.x;
  int u = blockIdx.x * 256 + t;
  int per = (nl + KC - 1) / KC;
  int ks = blockIdx.y * per;
  int ke = ks + per; if (ke > nl) ke = nl;
  float ub = 0, ux = 0, uy = 0, uz = 0;
  if (u < n0) {
    ub = pm[(size_t)u * 4]; ux = pm[(size_t)u * 4 + 1];
    uy = pm[(size_t)u * 4 + 2]; uz = pm[(size_t)u * 4 + 3];
  }
  float d0 = 3e38f, d1 = 3e38f, d2 = 3e38f;
  int i0 = -1, i1 = -1, i2 = -1;
  for (int base = ks; base < ke; base += 256) {
    int m = ke - base; if (m > 256) m = 256;
    __syncthreads();
    if (t < m) {
      const int* c = coords + (size_t)(base + t) * 4;
      kp[t] = make_float4((float)c[0],
                          OFFX + (c[3] + 0.5f) * vx,
                          OFFY + (c[2] + 0.5f) * vy,
                          OFFZ + (c[1] + 0.5f) * vz);
    }
    __syncthreads();
    if (u < n0) {
      for (int e = 0; e < m; e++) {
        float4 q = kp[e];
        float dx = ux - q.y, dy = uy - q.z, dz = uz - q.w;
        float d = dx * dx + dy * dy + dz * dz;
        if (q.x != ub) d += 1e10f;  // cross-batch penalty (matches reference)
        int gi = base + e;
        if (d < d2) {
          if (d < d1) {
            if (d < d0) { d2 = d1; i2 = i1; d1 = d0; i1 = i0; d0 = d; i0 = gi; }
            else        { d2 = d1; i2 = i1; d1 = d;  i1 = gi; }
          } else        { d2 = d;  i2 = gi; }
        }
      }
    }
  }
  if (u < n0) {
    size_t o = ((size_t)u * KC + blockIdx.y) * 3;
    pd[o] = d0; pd[o + 1] = d1; pd[o + 2] = d2;
    pi[o] = i0; pi[o + 1] = i1; pi[o + 2] = i2;
  }
}

__global__ void knn_merge_k(const float* __restrict__ pd, const int* __restrict__ pi, int n0,
                            float* __restrict__ wv, int* __restrict__ iv) {
  int u = blockIdx.x * 256 + threadIdx.x;
  if (u >= n0) return;
  float d0 = 3e38f, d1 = 3e38f, d2 = 3e38f;
  int i0 = -1, i1 = -1, i2 = -1;
  for (int c = 0; c < KC; c++) {
    size_t o = ((size_t)u * KC + c) * 3;
    for (int e = 0; e < 3; e++) {
      int gi = pi[o + e];
      if (gi < 0) continue;
      float d = pd[o + e];
      if (d < d2) {
        if (d < d1) {
          if (d < d0) { d2 = d1; i2 = i1; d1 = d0; i1 = i0; d0 = d; i0 = gi; }
          else        { d2 = d1; i2 = i1; d1 = d;  i1 = gi; }
        } else        { d2 = d;  i2 = gi; }
      }
    }
  }
  float w0 = 1.f / (d0 + 1e-8f), w1 = 1.f / (d1 + 1e-8f), w2 = 1.f / (d2 + 1e-8f);
  float s = w0 + w1 + w2;
  wv[(size_t)u * 3] = w0 / s; wv[(size_t)u * 3 + 1] = w1 / s; wv[(size_t)u * 3 + 2] = w2 / s;
  iv[(size_t)u * 3] = i0; iv[(size_t)u * 3 + 1] = i1; iv[(size_t)u * 3 + 2] = i2;
}

__global__ void interp_k(const float* __restrict__ f, int C, const float* __restrict__ wv,
                         const int* __restrict__ iv, int n0, float* __restrict__ X, int xoff) {
  int t = blockIdx.x * 256 + threadIdx.x;
  if (t >= n0 * C) return;
  int u = t / C, c = t % C;
  float r = wv[(size_t)u * 3]     * f[(size_t)iv[(size_t)u * 3]     * C + c]
          + wv[(size_t)u * 3 + 1] * f[(size_t)iv[(size_t)u * 3 + 1] * C + c]
          + wv[(size_t)u * 3 + 2] * f[(size_t)iv[(size_t)u * 3 + 2] * C + c];
  X[(size_t)u * 160 + xoff + c] = r;
}

// ---------------- extra 1x1 conv ----------------
__global__ void conv1x1_k(const float* __restrict__ f, const float* __restrict__ we, int n,
                          float* __restrict__ out) {
  int t = blockIdx.x * 256 + threadIdx.x;
  if (t >= n * 64) return;
  int p = t >> 6, co = t & 63;
  const float* fr = f + (size_t)p * 64;
  float a = 0.f;
#pragma unroll 16
  for (int ci = 0; ci < 64; ci++) a = fmaf(fr[ci], we[ci * 64 + co], a);
  out[t] = a;
}

// ---------------- dense scatter (B, 64*D3, H3, W3) ----------------
__global__ void scatter_k(const float* __restrict__ post, const int* __restrict__ c3, int n3,
                          float* __restrict__ out0) {
  int t = blockIdx.x * 256 + threadIdx.x;
  if (t >= n3 * 64) return;
  int p = t >> 6, c = t & 63;
  const int* cc = c3 + (size_t)p * 4;
  size_t o = ((((size_t)cc[0] * 64 + c) * 6 + cc[1]) * 100 + cc[2]) * 100 + cc[3];
  out0[o] = post[t];
}

// ---------------- head: pw = X @ fc_w.T ; cls/reg projections ----------------
__global__ void head_k(const float* __restrict__ X, const float* __restrict__ fcw,
                       const float* __restrict__ clsw, const float* __restrict__ regw,
                       int n0, float* __restrict__ outc, float* __restrict__ outr) {
  int wave = threadIdx.x >> 6, lane = threadIdx.x & 63;
  int u = blockIdx.x * 4 + wave;
  if (u >= n0) return;
  const float* xr = X + (size_t)u * 160;
  const float* wr = fcw + (size_t)lane * 160;
  float a = 0.f;
  for (int i = 0; i < 160; i++) a = fmaf(xr[i], wr[i], a);
  float c = a * clsw[lane];
  float r0 = a * regw[lane], r1 = a * regw[64 + lane], r2 = a * regw[128 + lane];
  for (int off = 32; off; off >>= 1) {
    c  += __shfl_down(c, off);
    r0 += __shfl_down(r0, off);
    r1 += __shfl_down(r1, off);
    r2 += __shfl_down(r2, off);
  }
  if (lane == 0) {
    outc[u] = c;
    outr[(size_t)u * 3] = r0; outr[(size_t)u * 3 + 1] = r1; outr[(size_t)u * 3 + 2] = r2;
  }
}

// ---------------- host ----------------
extern "C" void kernel_launch(void* const* d_in, const int* in_sizes, int n_in,
                              void* d_out, int out_size, void* d_ws, size_t ws_size,
                              hipStream_t stream) {
  const float* vf  = (const float*)d_in[0];
  const int* c0 = (const int*)d_in[1];
  const int* c1 = (const int*)d_in[2];
  const int* c2 = (const int*)d_in[3];
  const int* c3 = (const int*)d_in[4];
  const float* w00 = (const float*)d_in[5];  const float* b00 = (const float*)d_in[6];
  const float* w01 = (const float*)d_in[7];  const float* b01 = (const float*)d_in[8];
  const float* wd0 = (const float*)d_in[9];  const float* bd0 = (const float*)d_in[10];
  const float* w10 = (const float*)d_in[11]; const float* b10 = (const float*)d_in[12];
  const float* w11 = (const float*)d_in[13]; const float* b11 = (const float*)d_in[14];
  const float* wd1 = (const float*)d_in[15]; const float* bd1 = (const float*)d_in[16];
  const float* w20 = (const float*)d_in[17]; const float* b20 = (const float*)d_in[18];
  const float* w21 = (const float*)d_in[19]; const float* b21 = (const float*)d_in[20];
  const float* w22 = (const float*)d_in[21]; const float* b22 = (const float*)d_in[22];
  const float* wd2 = (const float*)d_in[23]; const float* bd2 = (const float*)d_in[24];
  const float* w30 = (const float*)d_in[25]; const float* b30 = (const float*)d_in[26];
  const float* w31 = (const float*)d_in[27]; const float* b31 = (const float*)d_in[28];
  const float* w32 = (const float*)d_in[29]; const float* b32 = (const float*)d_in[30];
  const float* we  = (const float*)d_in[31]; const float* be  = (const float*)d_in[32];
  const float* fcw = (const float*)d_in[33];
  const float* clsw = (const float*)d_in[34];
  const float* regw = (const float*)d_in[35];

  int N0 = in_sizes[1] / 4, N1 = in_sizes[2] / 4, N2 = in_sizes[3] / 4, N3 = in_sizes[4] / 4;
  int maxN = N0; if (N1 > maxN) maxN = N1; if (N2 > maxN) maxN = N2; if (N3 > maxN) maxN = N3;

  auto cdiv = [](int a, int b) { return (a + b - 1) / b; };
  char* p = (char*)d_ws;
  auto alloc = [&](size_t bytes) { char* r = p; p += (bytes + 255) & ~(size_t)255; return r; };

  int* keys0 = (int*)alloc((size_t)N0 * 4);
  int* keys1 = (int*)alloc((size_t)N1 * 4);
  int* keys2 = (int*)alloc((size_t)N2 * 4);
  int* keys3 = (int*)alloc((size_t)N3 * 4);
  int* nbr0  = (int*)alloc((size_t)N0 * 27 * 4);
  int* nbrs1 = (int*)alloc((size_t)N1 * 27 * 4);
  int* nbr1  = (int*)alloc((size_t)N1 * 27 * 4);
  int* nbrs2 = (int*)alloc((size_t)N2 * 27 * 4);
  int* nbr2  = (int*)alloc((size_t)N2 * 27 * 4);
  int* nbrs3 = (int*)alloc((size_t)N3 * 27 * 4);
  int* nbr3  = (int*)alloc((size_t)N3 * 27 * 4);
  float* FA = (float*)alloc((size_t)maxN * 64 * 4);
  float* FB = (float*)alloc((size_t)maxN * 64 * 4);
  float* FC = (float*)alloc((size_t)maxN * 64 * 4);
  float* part = (float*)alloc((size_t)NCH * 64 * 2 * 4);
  float* pd = (float*)alloc((size_t)N0 * KC * 3 * 4);
  int*   pi = (int*)alloc((size_t)N0 * KC * 3 * 4);
  float* wv = (float*)alloc((size_t)N0 * 3 * 4);
  int*   iv = (int*)alloc((size_t)N0 * 3 * 4);
  float* X  = (float*)alloc((size_t)N0 * 160 * 4);
  float* pmb = (float*)alloc((size_t)N0 * 4 * 4);

  float* out0 = (float*)d_out;
  float* out1 = out0 + 7680000;        // points_mean
  float* outc = out1 + (size_t)N0 * 4; // cls
  float* outr = outc + N0;             // reg

  // keys + neighbor tables
  keys_k<<<cdiv(N0, 256), 256, 0, stream>>>(c0, N0, 41, 800, 800, keys0);
  keys_k<<<cdiv(N1, 256), 256, 0, stream>>>(c1, N1, 21, 400, 400, keys1);
  keys_k<<<cdiv(N2, 256), 256, 0, stream>>>(c2, N2, 11, 200, 200, keys2);
  keys_k<<<cdiv(N3, 256), 256, 0, stream>>>(c3, N3, 6, 100, 100, keys3);
  nbr_k<<<cdiv(N0 * 27, 256), 256, 0, stream>>>(c0, N0, keys0, N0, 41, 800, 800, 1, nbr0);
  nbr_k<<<cdiv(N1 * 27, 256), 256, 0, stream>>>(c1, N1, keys0, N0, 41, 800, 800, 2, nbrs1);
  nbr_k<<<cdiv(N1 * 27, 256), 256, 0, stream>>>(c1, N1, keys1, N1, 21, 400, 400, 1, nbr1);
  nbr_k<<<cdiv(N2 * 27, 256), 256, 0, stream>>>(c2, N2, keys1, N1, 21, 400, 400, 2, nbrs2);
  nbr_k<<<cdiv(N2 * 27, 256), 256, 0, stream>>>(c2, N2, keys2, N2, 11, 200, 200, 1, nbr2);
  nbr_k<<<cdiv(N3 * 27, 256), 256, 0, stream>>>(c3, N3, keys2, N2, 11, 200, 200, 2, nbrs3);
  nbr_k<<<cdiv(N3 * 27, 256), 256, 0, stream>>>(c3, N3, keys3, N3, 6, 100, 100, 1, nbr3);
  pm_k<<<cdiv(N0, 256), 256, 0, stream>>>(vf, c0, N0, pmb, out1);

  auto conv = [&](const float* fin, const int* nb, const float* wptr, int n, int cin, int cout,
                  float* outp) {
    int blocks = cdiv(n, 32);
    if (cin == 4 && cout == 16)
      conv_k<4, 16><<<blocks, 256, 0, stream>>>(fin, nb, wptr, n, outp);
    else if (cin == 16 && cout == 16)
      conv_k<16, 16><<<blocks, 256, 0, stream>>>(fin, nb, wptr, n, outp);
    else if (cin == 16 && cout == 32)
      conv_k<16, 32><<<blocks, 256, 0, stream>>>(fin, nb, wptr, n, outp);
    else if (cin == 32 && cout == 32)
      conv_k<32, 32><<<blocks, 256, 0, stream>>>(fin, nb, wptr, n, outp);
    else if (cin == 32 && cout == 64)
      conv_k<32, 64><<<blocks, 256, 0, stream>>>(fin, nb, wptr, n, outp);
    else
      conv_k<64, 64><<<blocks, 256, 0, stream>>>(fin, nb, wptr, n, outp);
  };
  auto bn = [&](const float* pre, const float* bnp, int n, int C, float* post) {
    bnpart_k<<<dim3(1, NCH), 256, 0, stream>>>(pre, n, C, part);
    bnapply_k<<<cdiv(n * C, 256), 256, 0, stream>>>(pre, part, bnp, n, C, post);
  };
  auto knn = [&](const int* cl, int nl, float vx, float vy, float vz, const float* f, int C,
                 int xoff) {
    knn_part_k<<<dim3(cdiv(N0, 256), KC), 256, 0, stream>>>(pmb, N0, cl, nl, vx, vy, vz, pd, pi);
    knn_merge_k<<<cdiv(N0, 256), 256, 0, stream>>>(pd, pi, N0, wv, iv);
    interp_k<<<cdiv(N0 * C, 256), 256, 0, stream>>>(f, C, wv, iv, N0, X, xoff);
  };

  conv(vf, nbr0, w00, N0, 4, 16, FC);   bn(FC, b00, N0, 16, FA);
  conv(FA, nbr0, w01, N0, 16, 16, FC);  bn(FC, b01, N0, 16, FB);
  conv(FB, nbrs1, wd0, N1, 16, 32, FC); bn(FC, bd0, N1, 32, FA);
  conv(FA, nbr1, w10, N1, 32, 32, FC);  bn(FC, b10, N1, 32, FB);
  conv(FB, nbr1, w11, N1, 32, 32, FC);  bn(FC, b11, N1, 32, FA);
  knn(c1, N1, 0.2f, 0.2f, 0.4f, FA, 32, 0);
  conv(FA, nbrs2, wd1, N2, 32, 64, FC); bn(FC, bd1, N2, 64, FB);
  conv(FB, nbr2, w20, N2, 64, 64, FC);  bn(FC, b20, N2, 64, FA);
  conv(FA, nbr2, w21, N2, 64, 64, FC);  bn(FC, b21, N2, 64, FB);
  conv(FB, nbr2, w22, N2, 64, 64, FC);  bn(FC, b22, N2, 64, FA);
  knn(c2, N2, 0.4f, 0.4f, 0.8f, FA, 64, 32);
  conv(FA, nbrs3, wd2, N3, 64, 64, FC); bn(FC, bd2, N3, 64, FB);
  conv(FB, nbr3, w30, N3, 64, 64, FC);  bn(FC, b30, N3, 64, FA);
  conv(FA, nbr3, w31, N3, 64, 64, FC);  bn(FC, b31, N3, 64, FB);
  conv(FB, nbr3, w32, N3, 64, 64, FC);  bn(FC, b32, N3, 64, FA);
  knn(c3, N3, 0.8f, 0.8f, 1.6f, FA, 64, 96);

  conv1x1_k<<<cdiv(N3 * 64, 256), 256, 0, stream>>>(FA, we, N3, FC);
  bn(FC, be, N3, 64, FB);
  hipMemsetAsync(d_out, 0, (size_t)7680000 * 4, stream);
  scatter_k<<<cdiv(N3 * 64, 256), 256, 0, stream>>>(FB, c3, N3, out0);
  head_k<<<cdiv(N0, 4), 256, 0, stream>>>(X, fcw, clsw, regw, N0, outc, outr);
}

// Round 2
// 1703.083 us; speedup vs baseline: 1.4881x; 1.4881x over previous
//
#include <hip/hip_runtime.h>

#define OFFX 0.0f
#define OFFY -40.0f
#define OFFZ -3.0f
#define BNEPS 1e-3f
#define KC 16   // knn chunks over known points
#define NCH 64  // bn partial chunks
#define NG 9    // conv tap groups (3 taps each)

// ---------------- keys ----------------
__global__ void keys_k(const int* __restrict__ coords, int n, int D, int H, int W,
                       int* __restrict__ keys) {
  int i = blockIdx.x * 256 + threadIdx.x;
  if (i < n) {
    const int* c = coords + (size_t)i * 4;
    keys[i] = ((c[0] * D + c[1]) * H + c[2]) * W + c[3];
  }
}

// ---------------- neighbor tables (subm: scale=1, stride: scale=2) ----------------
__global__ void nbr_k(const int* __restrict__ coords, int np, const int* __restrict__ keys, int nk,
                      int D, int H, int W, int scale, int* __restrict__ nbr) {
  int t = blockIdx.x * 256 + threadIdx.x;
  if (t >= np * 27) return;
  int p = t / 27, k = t % 27;
  int kz = k / 9 - 1, ky = (k / 3) % 3 - 1, kx = k % 3 - 1;
  const int* c = coords + (size_t)p * 4;
  int z = c[1] * scale + kz, y = c[2] * scale + ky, x = c[3] * scale + kx;
  int r = -1;
  if (z >= 0 && z < D && y >= 0 && y < H && x >= 0 && x < W) {
    int q = ((c[0] * D + z) * H + y) * W + x;
    int lo = 0, hi = nk;
    while (lo < hi) { int m = (lo + hi) >> 1; if (keys[m] < q) lo = m + 1; else hi = m; }
    if (lo < nk && keys[lo] == q) r = lo;
  }
  nbr[t] = r;
}

// ---------------- sparse 3x3x3 conv, tap-group partials ----------------
// grid = (cdiv(n,P), NG); group g handles taps [3g, 3g+3); partial[g] += contribution.
template<int CIN, int COUT, int P>
__global__ __launch_bounds__(256) void conv_k(const float* __restrict__ feats,
                                              const int* __restrict__ nbr,
                                              const float* __restrict__ w, int n,
                                              float* __restrict__ partial, int gstride) {
  constexpr int PR = 64 / COUT;  // points sharing a wave row
  constexpr int PW = P / 4;      // points per wave
  constexpr int NI = PW / PR;    // points per thread
  __shared__ __align__(16) float wlds[CIN * COUT];
  int tid = threadIdx.x;
  int wave = tid >> 6, lane = tid & 63;
  int co = lane % COUT, j = lane / COUT;
  int pbase = blockIdx.x * P + wave * PW;
  int k0 = blockIdx.y * 3, k1 = k0 + 3;  // NG*3 == 27
  float acc[NI];
#pragma unroll
  for (int i = 0; i < NI; i++) acc[i] = 0.f;
  for (int k = k0; k < k1; k++) {
    __syncthreads();
    for (int i = tid; i < CIN * COUT / 4; i += 256)
      ((float4*)wlds)[i] = ((const float4*)w)[(size_t)k * (CIN * COUT / 4) + i];
    __syncthreads();
#pragma unroll
    for (int i = 0; i < NI; i++) {
      int p = pbase + i * PR + j;
      if (p >= n) continue;
      int idx = nbr[(size_t)p * 27 + k];
      if (idx < 0) continue;
      const float* fr = feats + (size_t)idx * CIN;
#pragma unroll
      for (int c4 = 0; c4 < CIN / 4; c4++) {
        float4 fv = *(const float4*)(fr + c4 * 4);
        acc[i] = fmaf(fv.x, wlds[(c4 * 4 + 0) * COUT + co], acc[i]);
        acc[i] = fmaf(fv.y, wlds[(c4 * 4 + 1) * COUT + co], acc[i]);
        acc[i] = fmaf(fv.z, wlds[(c4 * 4 + 2) * COUT + co], acc[i]);
        acc[i] = fmaf(fv.w, wlds[(c4 * 4 + 3) * COUT + co], acc[i]);
      }
    }
  }
#pragma unroll
  for (int i = 0; i < NI; i++) {
    int p = pbase + i * PR + j;
    if (p < n) partial[(size_t)blockIdx.y * gstride + (size_t)p * COUT + co] = acc[i];
  }
}

// ---------------- batchnorm: sum partials + stats, then finalize+apply ----------------
__global__ void bnpart_k(const float* __restrict__ partial, int G, int gstride, int n, int C,
                         float* __restrict__ pre, float* __restrict__ stats) {
  __shared__ float l1[256], l2[256];
  int t = threadIdx.x;
  int total = n * C;
  float s1 = 0.f, s2 = 0.f;
  for (int i = blockIdx.x * 256 + t; i < total; i += NCH * 256) {
    float v = 0.f;
    for (int g = 0; g < G; g++) v += partial[(size_t)g * gstride + i];
    pre[i] = v;
    s1 += v; s2 += v * v;
  }
  l1[t] = s1; l2[t] = s2;
  for (int s = 128; s >= C; s >>= 1) {
    __syncthreads();
    if (t < s) { l1[t] += l1[t + s]; l2[t] += l2[t + s]; }
  }
  __syncthreads();
  if (t < C) {
    stats[((size_t)blockIdx.x * C + t) * 2] = l1[t];
    stats[((size_t)blockIdx.x * C + t) * 2 + 1] = l2[t];
  }
}

__global__ void bnapply_k(const float* __restrict__ pre, const float* __restrict__ stats,
                          const float* __restrict__ bnp, int n, int C, float* __restrict__ post) {
  __shared__ float sc[128];
  int t = threadIdx.x;
  if (t < C) {
    float s1 = 0.f, s2 = 0.f;
    for (int ch = 0; ch < NCH; ch++) {
      s1 += stats[((size_t)ch * C + t) * 2];
      s2 += stats[((size_t)ch * C + t) * 2 + 1];
    }
    float m = s1 / n;
    float v = s2 / n - m * m;
    float scale = bnp[t] / sqrtf(v + BNEPS);
    sc[t] = scale;
    sc[64 + t] = bnp[C + t] - m * scale;
  }
  __syncthreads();
  size_t i = (size_t)blockIdx.x * 256 + t;
  if (i < (size_t)n * C) {
    int c = (int)(i % C);
    float v = pre[i] * sc[c] + sc[64 + c];
    post[i] = v > 0.f ? v : 0.f;
  }
}

// ---------------- points_mean ----------------
__global__ void pm_k(const float* __restrict__ vf, const int* __restrict__ c0, int n0,
                     float* __restrict__ pm, float* __restrict__ out1) {
  int i = blockIdx.x * 256 + threadIdx.x;
  if (i >= n0) return;
  float b = (float)c0[(size_t)i * 4];
  float x = vf[(size_t)i * 4], y = vf[(size_t)i * 4 + 1], z = vf[(size_t)i * 4 + 2];
  pm[(size_t)i * 4] = b; pm[(size_t)i * 4 + 1] = x; pm[(size_t)i * 4 + 2] = y; pm[(size_t)i * 4 + 3] = z;
  out1[(size_t)i * 4] = b; out1[(size_t)i * 4 + 1] = x; out1[(size_t)i * 4 + 2] = y; out1[(size_t)i * 4 + 3] = z;
}

// ---------------- 3-NN: per-chunk top-3 then merge ----------------
__global__ void knn_part_k(const float* __restrict__ pm, int n0, const int* __restrict__ coords, int nl,
                           float vx, float vy, float vz,
                           float* __restrict__ pd, int* __restrict__ pi) {
  __shared__ __align__(16) float4 kp[256];
  int t = threadIdx.x;
  int u = blockIdx.x * 256 + t;
  int per = (nl + KC - 1) / KC;
  int ks = blockIdx.y * per;
  int ke = ks + per; if (ke > nl) ke = nl;
  float ub = 0, ux = 0, uy = 0, uz = 0;
  if (u < n0) {
    ub = pm[(size_t)u * 4]; ux = pm[(size_t)u * 4 + 1];
    uy = pm[(size_t)u * 4 + 2]; uz = pm[(size_t)u * 4 + 3];
  }
  float d0 = 3e38f, d1 = 3e38f, d2 = 3e38f;
  int i0 = -1, i1 = -1, i2 = -1;
  for (int base = ks; base < ke; base += 256) {
    int m = ke - base; if (m > 256) m = 256;
    __syncthreads();
    if (t < m) {
      const int* c = coords + (size_t)(base + t) * 4;
      kp[t] = make_float4((float)c[0],
                          OFFX + (c[3] + 0.5f) * vx,
                          OFFY + (c[2] + 0.5f) * vy,
                          OFFZ + (c[1] + 0.5f) * vz);
    }
    __syncthreads();
    if (u < n0) {
      for (int e = 0; e < m; e++) {
        float4 q = kp[e];
        float dx = ux - q.y, dy = uy - q.z, dz = uz - q.w;
        float d = dx * dx + dy * dy + dz * dz;
        if (q.x != ub) d += 1e10f;  // cross-batch penalty (matches reference)
        int gi = base + e;
        if (d < d2) {
          if (d < d1) {
            if (d < d0) { d2 = d1; i2 = i1; d1 = d0; i1 = i0; d0 = d; i0 = gi; }
            else        { d2 = d1; i2 = i1; d1 = d;  i1 = gi; }
          } else        { d2 = d;  i2 = gi; }
        }
      }
    }
  }
  if (u < n0) {
    size_t o = ((size_t)u * KC + blockIdx.y) * 3;
    pd[o] = d0; pd[o + 1] = d1; pd[o + 2] = d2;
    pi[o] = i0; pi[o + 1] = i1; pi[o + 2] = i2;
  }
}

__global__ void knn_merge_k(const float* __restrict__ pd, const int* __restrict__ pi, int n0,
                            float* __restrict__ wv, int* __restrict__ iv) {
  int u = blockIdx.x * 256 + threadIdx.x;
  if (u >= n0) return;
  float d0 = 3e38f, d1 = 3e38f, d2 = 3e38f;
  int i0 = -1, i1 = -1, i2 = -1;
  for (int c = 0; c < KC; c++) {
    size_t o = ((size_t)u * KC + c) * 3;
    for (int e = 0; e < 3; e++) {
      int gi = pi[o + e];
      if (gi < 0) continue;
      float d = pd[o + e];
      if (d < d2) {
        if (d < d1) {
          if (d < d0) { d2 = d1; i2 = i1; d1 = d0; i1 = i0; d0 = d; i0 = gi; }
          else        { d2 = d1; i2 = i1; d1 = d;  i1 = gi; }
        } else        { d2 = d;  i2 = gi; }
      }
    }
  }
  float w0 = 1.f / (d0 + 1e-8f), w1 = 1.f / (d1 + 1e-8f), w2 = 1.f / (d2 + 1e-8f);
  float s = w0 + w1 + w2;
  wv[(size_t)u * 3] = w0 / s; wv[(size_t)u * 3 + 1] = w1 / s; wv[(size_t)u * 3 + 2] = w2 / s;
  iv[(size_t)u * 3] = i0; iv[(size_t)u * 3 + 1] = i1; iv[(size_t)u * 3 + 2] = i2;
}

__global__ void interp_k(const float* __restrict__ f, int C, const float* __restrict__ wv,
                         const int* __restrict__ iv, int n0, float* __restrict__ X, int xoff) {
  int t = blockIdx.x * 256 + threadIdx.x;
  if (t >= n0 * C) return;
  int u = t / C, c = t % C;
  float r = wv[(size_t)u * 3]     * f[(size_t)iv[(size_t)u * 3]     * C + c]
          + wv[(size_t)u * 3 + 1] * f[(size_t)iv[(size_t)u * 3 + 1] * C + c]
          + wv[(size_t)u * 3 + 2] * f[(size_t)iv[(size_t)u * 3 + 2] * C + c];
  X[(size_t)u * 160 + xoff + c] = r;
}

// ---------------- extra 1x1 conv ----------------
__global__ void conv1x1_k(const float* __restrict__ f, const float* __restrict__ we, int n,
                          float* __restrict__ out) {
  int t = blockIdx.x * 256 + threadIdx.x;
  if (t >= n * 64) return;
  int p = t >> 6, co = t & 63;
  const float* fr = f + (size_t)p * 64;
  float a = 0.f;
#pragma unroll 16
  for (int ci = 0; ci < 64; ci++) a = fmaf(fr[ci], we[ci * 64 + co], a);
  out[t] = a;
}

// ---------------- dense scatter (B, 64*D3, H3, W3) ----------------
__global__ void scatter_k(const float* __restrict__ post, const int* __restrict__ c3, int n3,
                          float* __restrict__ out0) {
  int t = blockIdx.x * 256 + threadIdx.x;
  if (t >= n3 * 64) return;
  int p = t >> 6, c = t & 63;
  const int* cc = c3 + (size_t)p * 4;
  size_t o = ((((size_t)cc[0] * 64 + c) * 6 + cc[1]) * 100 + cc[2]) * 100 + cc[3];
  out0[o] = post[t];
}

// ---------------- head: pw = X @ fc_w.T ; cls/reg projections ----------------
__global__ void head_k(const float* __restrict__ X, const float* __restrict__ fcw,
                       const float* __restrict__ clsw, const float* __restrict__ regw,
                       int n0, float* __restrict__ outc, float* __restrict__ outr) {
  int wave = threadIdx.x >> 6, lane = threadIdx.x & 63;
  int u = blockIdx.x * 4 + wave;
  if (u >= n0) return;
  const float* xr = X + (size_t)u * 160;
  const float* wr = fcw + (size_t)lane * 160;
  float a = 0.f;
  for (int i = 0; i < 160; i++) a = fmaf(xr[i], wr[i], a);
  float c = a * clsw[lane];
  float r0 = a * regw[lane], r1 = a * regw[64 + lane], r2 = a * regw[128 + lane];
  for (int off = 32; off; off >>= 1) {
    c  += __shfl_down(c, off);
    r0 += __shfl_down(r0, off);
    r1 += __shfl_down(r1, off);
    r2 += __shfl_down(r2, off);
  }
  if (lane == 0) {
    outc[u] = c;
    outr[(size_t)u * 3] = r0; outr[(size_t)u * 3 + 1] = r1; outr[(size_t)u * 3 + 2] = r2;
  }
}

// ---------------- host ----------------
extern "C" void kernel_launch(void* const* d_in, const int* in_sizes, int n_in,
                              void* d_out, int out_size, void* d_ws, size_t ws_size,
                              hipStream_t stream) {
  const float* vf  = (const float*)d_in[0];
  const int* c0 = (const int*)d_in[1];
  const int* c1 = (const int*)d_in[2];
  const int* c2 = (const int*)d_in[3];
  const int* c3 = (const int*)d_in[4];
  const float* w00 = (const float*)d_in[5];  const float* b00 = (const float*)d_in[6];
  const float* w01 = (const float*)d_in[7];  const float* b01 = (const float*)d_in[8];
  const float* wd0 = (const float*)d_in[9];  const float* bd0 = (const float*)d_in[10];
  const float* w10 = (const float*)d_in[11]; const float* b10 = (const float*)d_in[12];
  const float* w11 = (const float*)d_in[13]; const float* b11 = (const float*)d_in[14];
  const float* wd1 = (const float*)d_in[15]; const float* bd1 = (const float*)d_in[16];
  const float* w20 = (const float*)d_in[17]; const float* b20 = (const float*)d_in[18];
  const float* w21 = (const float*)d_in[19]; const float* b21 = (const float*)d_in[20];
  const float* w22 = (const float*)d_in[21]; const float* b22 = (const float*)d_in[22];
  const float* wd2 = (const float*)d_in[23]; const float* bd2 = (const float*)d_in[24];
  const float* w30 = (const float*)d_in[25]; const float* b30 = (const float*)d_in[26];
  const float* w31 = (const float*)d_in[27]; const float* b31 = (const float*)d_in[28];
  const float* w32 = (const float*)d_in[29]; const float* b32 = (const float*)d_in[30];
  const float* we  = (const float*)d_in[31]; const float* be  = (const float*)d_in[32];
  const float* fcw = (const float*)d_in[33];
  const float* clsw = (const float*)d_in[34];
  const float* regw = (const float*)d_in[35];

  int N0 = in_sizes[1] / 4, N1 = in_sizes[2] / 4, N2 = in_sizes[3] / 4, N3 = in_sizes[4] / 4;
  int maxN = N0; if (N1 > maxN) maxN = N1; if (N2 > maxN) maxN = N2; if (N3 > maxN) maxN = N3;

  auto cdiv = [](int a, int b) { return (a + b - 1) / b; };
  char* p = (char*)d_ws;
  auto alloc = [&](size_t bytes) { char* r = p; p += (bytes + 255) & ~(size_t)255; return r; };

  int* keys0 = (int*)alloc((size_t)N0 * 4);
  int* keys1 = (int*)alloc((size_t)N1 * 4);
  int* keys2 = (int*)alloc((size_t)N2 * 4);
  int* keys3 = (int*)alloc((size_t)N3 * 4);
  int* nbr0  = (int*)alloc((size_t)N0 * 27 * 4);
  int* nbrs1 = (int*)alloc((size_t)N1 * 27 * 4);
  int* nbr1  = (int*)alloc((size_t)N1 * 27 * 4);
  int* nbrs2 = (int*)alloc((size_t)N2 * 27 * 4);
  int* nbr2  = (int*)alloc((size_t)N2 * 27 * 4);
  int* nbrs3 = (int*)alloc((size_t)N3 * 27 * 4);
  int* nbr3  = (int*)alloc((size_t)N3 * 27 * 4);
  float* FA = (float*)alloc((size_t)maxN * 64 * 4);
  float* FB = (float*)alloc((size_t)maxN * 64 * 4);
  float* FC = (float*)alloc((size_t)maxN * 64 * 4);
  float* stats = (float*)alloc((size_t)NCH * 64 * 2 * 4);
  float* pd = (float*)alloc((size_t)N0 * KC * 3 * 4);
  int*   pi = (int*)alloc((size_t)N0 * KC * 3 * 4);
  float* wv = (float*)alloc((size_t)N0 * 3 * 4);
  int*   iv = (int*)alloc((size_t)N0 * 3 * 4);
  float* X  = (float*)alloc((size_t)N0 * 160 * 4);
  float* pmb = (float*)alloc((size_t)N0 * 4 * 4);

  float* out0 = (float*)d_out;
  float* out1 = out0 + 7680000;        // points_mean
  float* outc = out1 + (size_t)N0 * 4; // cls
  float* outr = outc + N0;             // reg
  // dense-output region doubles as conv partial-sum scratch until the final memset
  float* partial = out0;  // NG * n * COUT floats needed; max ~ NG*maxN*64 < 7.68M

  // keys + neighbor tables
  keys_k<<<cdiv(N0, 256), 256, 0, stream>>>(c0, N0, 41, 800, 800, keys0);
  keys_k<<<cdiv(N1, 256), 256, 0, stream>>>(c1, N1, 21, 400, 400, keys1);
  keys_k<<<cdiv(N2, 256), 256, 0, stream>>>(c2, N2, 11, 200, 200, keys2);
  keys_k<<<cdiv(N3, 256), 256, 0, stream>>>(c3, N3, 6, 100, 100, keys3);
  nbr_k<<<cdiv(N0 * 27, 256), 256, 0, stream>>>(c0, N0, keys0, N0, 41, 800, 800, 1, nbr0);
  nbr_k<<<cdiv(N1 * 27, 256), 256, 0, stream>>>(c1, N1, keys0, N0, 41, 800, 800, 2, nbrs1);
  nbr_k<<<cdiv(N1 * 27, 256), 256, 0, stream>>>(c1, N1, keys1, N1, 21, 400, 400, 1, nbr1);
  nbr_k<<<cdiv(N2 * 27, 256), 256, 0, stream>>>(c2, N2, keys1, N1, 21, 400, 400, 2, nbrs2);
  nbr_k<<<cdiv(N2 * 27, 256), 256, 0, stream>>>(c2, N2, keys2, N2, 11, 200, 200, 1, nbr2);
  nbr_k<<<cdiv(N3 * 27, 256), 256, 0, stream>>>(c3, N3, keys2, N2, 11, 200, 200, 2, nbrs3);
  nbr_k<<<cdiv(N3 * 27, 256), 256, 0, stream>>>(c3, N3, keys3, N3, 6, 100, 100, 1, nbr3);
  pm_k<<<cdiv(N0, 256), 256, 0, stream>>>(vf, c0, N0, pmb, out1);

  auto conv = [&](const float* fin, const int* nb, const float* wptr, int n, int cin, int cout) {
    dim3 g32(cdiv(n, 32), NG), g16(cdiv(n, 16), NG);
    bool big = n >= 4096;
    int gs = n * cout;
    if (cin == 4 && cout == 16) {
      if (big) conv_k<4, 16, 32><<<g32, 256, 0, stream>>>(fin, nb, wptr, n, partial, gs);
      else     conv_k<4, 16, 16><<<g16, 256, 0, stream>>>(fin, nb, wptr, n, partial, gs);
    } else if (cin == 16 && cout == 16) {
      if (big) conv_k<16, 16, 32><<<g32, 256, 0, stream>>>(fin, nb, wptr, n, partial, gs);
      else     conv_k<16, 16, 16><<<g16, 256, 0, stream>>>(fin, nb, wptr, n, partial, gs);
    } else if (cin == 16 && cout == 32) {
      if (big) conv_k<16, 32, 32><<<g32, 256, 0, stream>>>(fin, nb, wptr, n, partial, gs);
      else     conv_k<16, 32, 16><<<g16, 256, 0, stream>>>(fin, nb, wptr, n, partial, gs);
    } else if (cin == 32 && cout == 32) {
      if (big) conv_k<32, 32, 32><<<g32, 256, 0, stream>>>(fin, nb, wptr, n, partial, gs);
      else     conv_k<32, 32, 16><<<g16, 256, 0, stream>>>(fin, nb, wptr, n, partial, gs);
    } else if (cin == 32 && cout == 64) {
      if (big) conv_k<32, 64, 32><<<g32, 256, 0, stream>>>(fin, nb, wptr, n, partial, gs);
      else     conv_k<32, 64, 16><<<g16, 256, 0, stream>>>(fin, nb, wptr, n, partial, gs);
    } else {
      if (big) conv_k<64, 64, 32><<<g32, 256, 0, stream>>>(fin, nb, wptr, n, partial, gs);
      else     conv_k<64, 64, 16><<<g16, 256, 0, stream>>>(fin, nb, wptr, n, partial, gs);
    }
  };
  // conv partials -> summed pre (FC) + stats; then scale/shift/relu -> post
  auto bnp = [&](const float* bnpar, int n, int C, float* post) {
    bnpart_k<<<NCH, 256, 0, stream>>>(partial, NG, n * C, n, C, FC, stats);
    bnapply_k<<<cdiv(n * C, 256), 256, 0, stream>>>(FC, stats, bnpar, n, C, post);
  };
  auto knn = [&](const int* cl, int nl, float vx, float vy, float vz, const float* f, int C,
                 int xoff) {
    knn_part_k<<<dim3(cdiv(N0, 256), KC), 256, 0, stream>>>(pmb, N0, cl, nl, vx, vy, vz, pd, pi);
    knn_merge_k<<<cdiv(N0, 256), 256, 0, stream>>>(pd, pi, N0, wv, iv);
    interp_k<<<cdiv(N0 * C, 256), 256, 0, stream>>>(f, C, wv, iv, N0, X, xoff);
  };

  conv(vf, nbr0, w00, N0, 4, 16);   bnp(b00, N0, 16, FA);
  conv(FA, nbr0, w01, N0, 16, 16);  bnp(b01, N0, 16, FB);
  conv(FB, nbrs1, wd0, N1, 16, 32); bnp(bd0, N1, 32, FA);
  conv(FA, nbr1, w10, N1, 32, 32);  bnp(b10, N1, 32, FB);
  conv(FB, nbr1, w11, N1, 32, 32);  bnp(b11, N1, 32, FA);
  knn(c1, N1, 0.2f, 0.2f, 0.4f, FA, 32, 0);
  conv(FA, nbrs2, wd1, N2, 32, 64); bnp(bd1, N2, 64, FB);
  conv(FB, nbr2, w20, N2, 64, 64);  bnp(b20, N2, 64, FA);
  conv(FA, nbr2, w21, N2, 64, 64);  bnp(b21, N2, 64, FB);
  conv(FB, nbr2, w22, N2, 64, 64);  bnp(b22, N2, 64, FA);
  knn(c2, N2, 0.4f, 0.4f, 0.8f, FA, 64, 32);
  conv(FA, nbrs3, wd2, N3, 64, 64); bnp(bd2, N3, 64, FB);
  conv(FB, nbr3, w30, N3, 64, 64);  bnp(b30, N3, 64, FA);
  conv(FA, nbr3, w31, N3, 64, 64);  bnp(b31, N3, 64, FB);
  conv(FB, nbr3, w32, N3, 64, 64);  bnp(b32, N3, 64, FA);
  knn(c3, N3, 0.8f, 0.8f, 1.6f, FA, 64, 96);

  conv1x1_k<<<cdiv(N3 * 64, 256), 256, 0, stream>>>(FA, we, N3, FC);
  bnpart_k<<<NCH, 256, 0, stream>>>(FC, 1, 0, N3, 64, FC, stats);
  bnapply_k<<<cdiv(N3 * 64, 256), 256, 0, stream>>>(FC, stats, be, N3, 64, FB);
  hipMemsetAsync(d_out, 0, (size_t)7680000 * 4, stream);
  scatter_k<<<cdiv(N3 * 64, 256), 256, 0, stream>>>(FB, c3, N3, out0);
  head_k<<<cdiv(N0, 4), 256, 0, stream>>>(X, fcw, clsw, regw, N0, outc, outr);
}